// Round 1
// 1702.108 us; speedup vs baseline: 1.0339x; 1.0339x over previous
//
#include <hip/hip_runtime.h>
#include <hip/hip_bf16.h>

#define NU 100000
#define NI 50000
#define NF 512
#define DIM 32
#define ES 3200000
#define EU 3200000
#define NP 1000000
#define CHUNK 1024
#define NCH 98   // ceil(NU/CHUNK)

// ---- bucketed scatter params ----
#define ABK 32          // buckets per matrix
#define BRNG 3125       // rows per bucket; 32*3125 == 100000 exactly
#define EHALF 1600000   // edges per half-phase
#define ACAP 52000      // per-bucket capacity per half (mean 50000, +9 sigma)
#define ATILE 2048      // edges per phase-A block

typedef short bf16x8 __attribute__((ext_vector_type(8)));
typedef float f32x4 __attribute__((ext_vector_type(4)));

__device__ __forceinline__ float s2f(short s) {
    unsigned u = ((unsigned)(unsigned short)s) << 16;
    return __uint_as_float(u);
}
// f32 -> bf16 bits, round-to-nearest-even (inputs are finite; no NaN path)
__device__ __forceinline__ short f2bf(float f) {
    unsigned u = __float_as_uint(f);
    return (short)((u + 0x7FFFu + ((u >> 16) & 1u)) >> 16);
}

// ---------------- colsum of W (512x32 f32) -> wsum[32] f32 ----------------
__global__ void wsum_kernel(const float* __restrict__ W, float* __restrict__ wsum) {
    int c = threadIdx.x;
    if (c >= DIM) return;
    float s = 0.f;
    for (int k = 0; k < NF; ++k) s += W[k * DIM + c];
    wsum[c] = s;
}

// ------------- MFMA GEMM: RAW = bf16(X) @ bf16(W)  (+ sum/sumsq of X) ------
__global__ __launch_bounds__(256) void gemm_stats_kernel(
    const float* __restrict__ X, const float* __restrict__ W,
    float* __restrict__ RAW, float* __restrict__ statSum, float* __restrict__ statSq,
    int M)
{
    __shared__ short bfrag[16384];  // 16 ksteps x 2 ntiles x 64 lanes x 8 bf16
    for (int idx = threadIdx.x; idx < 16384; idx += 256) {
        int j = idx & 7;
        int lane = (idx >> 3) & 63;
        int t = (idx >> 9) & 1;
        int s = idx >> 10;
        int k = s * 32 + ((lane >> 4) << 3) + j;   // B[k][n]: k = quad*8+j per kstep
        int n = t * 16 + (lane & 15);
        bfrag[idx] = f2bf(W[k * DIM + n]);
    }
    __syncthreads();

    const int wave = threadIdx.x >> 6;
    const int lane = threadIdx.x & 63;
    const int quad = lane >> 4;
    const int mrow = lane & 15;

    bf16x8 ones;
#pragma unroll
    for (int j = 0; j < 8; ++j) ones[j] = (short)0x3F80;  // bf16 1.0

    float lsum = 0.f, lsq = 0.f;
    const int nstrips = M >> 4;
    for (int strip = blockIdx.x * 4 + wave; strip < nstrips; strip += gridDim.x * 4) {
        const float* arow = X + (size_t)(strip * 16 + mrow) * NF + quad * 8;
        f32x4 acc0 = {0.f, 0.f, 0.f, 0.f};
        f32x4 acc1 = {0.f, 0.f, 0.f, 0.f};
        f32x4 accR = {0.f, 0.f, 0.f, 0.f};
        f32x4 accG = {0.f, 0.f, 0.f, 0.f};
#pragma unroll
        for (int s = 0; s < 16; ++s) {
            float4 a0 = *(const float4*)(arow + s * 32);
            float4 a1 = *(const float4*)(arow + s * 32 + 4);
            bf16x8 a;
            a[0] = f2bf(a0.x); a[1] = f2bf(a0.y); a[2] = f2bf(a0.z); a[3] = f2bf(a0.w);
            a[4] = f2bf(a1.x); a[5] = f2bf(a1.y); a[6] = f2bf(a1.z); a[7] = f2bf(a1.w);
            bf16x8 b0 = *(const bf16x8*)(bfrag + (s * 2 + 0) * 512 + lane * 8);
            bf16x8 b1 = *(const bf16x8*)(bfrag + (s * 2 + 1) * 512 + lane * 8);
            acc0 = __builtin_amdgcn_mfma_f32_16x16x32_bf16(a, b0, acc0, 0, 0, 0);
            acc1 = __builtin_amdgcn_mfma_f32_16x16x32_bf16(a, b1, acc1, 0, 0, 0);
            accR = __builtin_amdgcn_mfma_f32_16x16x32_bf16(a, ones, accR, 0, 0, 0);
            accG = __builtin_amdgcn_mfma_f32_16x16x32_bf16(a, a, accG, 0, 0, 0);
        }
        float* outp = RAW + (size_t)strip * 16 * DIM;
#pragma unroll
        for (int i = 0; i < 4; ++i) {
            int r = quad * 4 + i;        // C/D: row = quad*4 + reg, col = lane&15
            outp[r * DIM + mrow]      = acc0[i];
            outp[r * DIM + 16 + mrow] = acc1[i];
        }
        if (mrow == 0) lsum += (accR[0] + accR[1]) + (accR[2] + accR[3]);
        int dg = mrow - quad * 4;        // Gram diagonal: col==row -> row sumsq
        if (dg >= 0 && dg < 4) lsq += accG[dg];
    }
#pragma unroll
    for (int off = 32; off > 0; off >>= 1) {
        lsum += __shfl_down(lsum, off);
        lsq  += __shfl_down(lsq, off);
    }
    if (lane == 0) { atomicAdd(statSum, lsum); atomicAdd(statSq, lsq); }
}

// ---- z=(raw - mu*wsum_c)/sigma + b_c; s=sigmoid(z); buf=s; stats of s -----
__global__ __launch_bounds__(256) void signorm_kernel(
    float* __restrict__ buf, int n4, float nx,
    const float* __restrict__ statsIn, const float* __restrict__ wsum,
    const float* __restrict__ bias, float* __restrict__ statsOut)
{
    float mu  = statsIn[0] / nx;
    float var = (statsIn[1] - nx * mu * mu) / (nx - 1.f);
    float inv = 1.f / sqrtf(var);
    float ls = 0.f, lsq = 0.f;
    int stride = gridDim.x * blockDim.x;
    for (int i = blockIdx.x * blockDim.x + threadIdx.x; i < n4; i += stride) {
        float4 v = ((const float4*)buf)[i];
        int c0 = (i << 2) & 31;
        float4 r;
        r.x = 1.f / (1.f + expf(-((v.x - mu * wsum[c0 + 0]) * inv + bias[c0 + 0])));
        r.y = 1.f / (1.f + expf(-((v.y - mu * wsum[c0 + 1]) * inv + bias[c0 + 1])));
        r.z = 1.f / (1.f + expf(-((v.z - mu * wsum[c0 + 2]) * inv + bias[c0 + 2])));
        r.w = 1.f / (1.f + expf(-((v.w - mu * wsum[c0 + 3]) * inv + bias[c0 + 3])));
        ((float4*)buf)[i] = r;
        ls  += (r.x + r.y) + (r.z + r.w);
        lsq += (r.x * r.x + r.y * r.y) + (r.z * r.z + r.w * r.w);
    }
#pragma unroll
    for (int off = 32; off > 0; off >>= 1) {
        ls  += __shfl_down(ls, off);
        lsq += __shfl_down(lsq, off);
    }
    if ((threadIdx.x & 63) == 0) { atomicAdd(statsOut + 0, ls); atomicAdd(statsOut + 1, lsq); }
}

// ----------- buf = (buf - mu)/sigma + emb  (global normalize of s) ---------
__global__ __launch_bounds__(256) void fusion_kernel(
    float* __restrict__ buf, const float* __restrict__ emb, int n4, float n,
    const float* __restrict__ statsIn)
{
    float mu  = statsIn[0] / n;
    float var = (statsIn[1] - n * mu * mu) / (n - 1.f);
    float inv = 1.f / sqrtf(var);
    int stride = gridDim.x * blockDim.x;
    for (int i = blockIdx.x * blockDim.x + threadIdx.x; i < n4; i += stride) {
        float4 v = ((const float4*)buf)[i];
        float4 e = ((const float4*)emb)[i];
        v.x = (v.x - mu) * inv + e.x;
        v.y = (v.y - mu) * inv + e.y;
        v.z = (v.z - mu) * inv + e.z;
        v.w = (v.w - mu) * inv + e.w;
        ((float4*)buf)[i] = v;
    }
}

// --------------------------- CSR construction -----------------------------
__global__ void hist_kernel(const int* __restrict__ sr, const int* __restrict__ ur,
                            int* __restrict__ cntS, int* __restrict__ cntU)
{
    int i = blockIdx.x * 256 + threadIdx.x;
    if (i < ES) atomicAdd(cntS + sr[i], 1);
    else        atomicAdd(cntU + ur[i - ES], 1);
}

__global__ void chunksum_kernel(const int* __restrict__ cntS, const int* __restrict__ cntU,
                                int* __restrict__ csS, int* __restrict__ csU)
{
    int b = blockIdx.x;
    const int* cnt; int* cs; int c;
    if (b < NCH) { cnt = cntS; cs = csS; c = b; }
    else         { cnt = cntU; cs = csU; c = b - NCH; }
    int base = c * CHUNK;
    int v = 0;
    for (int t = threadIdx.x; t < CHUNK; t += 256) {
        int i = base + t;
        if (i < NU) v += cnt[i];
    }
#pragma unroll
    for (int off = 32; off > 0; off >>= 1) v += __shfl_down(v, off);
    __shared__ int sm[4];
    if ((threadIdx.x & 63) == 0) sm[threadIdx.x >> 6] = v;
    __syncthreads();
    if (threadIdx.x == 0) cs[c] = sm[0] + sm[1] + sm[2] + sm[3];
}

__global__ void scan_offsets_kernel(int* __restrict__ csS, int* __restrict__ csU,
                                    int* __restrict__ rpS, int* __restrict__ rpU)
{
    if (threadIdx.x == 0) {
        int run = 0;
        for (int c = 0; c < NCH; ++c) { int t = csS[c]; csS[c] = run; run += t; }
        rpS[NU] = run;
    }
    if (threadIdx.x == 1) {
        int run = 0;
        for (int c = 0; c < NCH; ++c) { int t = csU[c]; csU[c] = run; run += t; }
        rpU[NU] = run;
    }
}

__global__ __launch_bounds__(1024) void chunkscan_kernel(
    const int* __restrict__ cntS, const int* __restrict__ cntU,
    const int* __restrict__ csS, const int* __restrict__ csU,
    int* __restrict__ rpS, int* __restrict__ rpU)
{
    int b = blockIdx.x;
    const int* cnt; const int* cs; int* rp; int c;
    if (b < NCH) { cnt = cntS; cs = csS; rp = rpS; c = b; }
    else         { cnt = cntU; cs = csU; rp = rpU; c = b - NCH; }
    int i = c * CHUNK + threadIdx.x;
    int v = (i < NU) ? cnt[i] : 0;
    __shared__ int sm[CHUNK];
    sm[threadIdx.x] = v;
    __syncthreads();
    for (int off = 1; off < CHUNK; off <<= 1) {
        int t = (threadIdx.x >= off) ? sm[threadIdx.x - off] : 0;
        __syncthreads();
        sm[threadIdx.x] += t;
        __syncthreads();
    }
    if (i < NU) rp[i] = cs[c] + sm[threadIdx.x] - v;  // exclusive scan
}

// ---------------- phase A: partition edges into 32 row-buckets -------------
// Record: u32 w = (bf16(val)<<17)|col  (identical to final CSR word),
//         u16 rl = row - bucket*BRNG.
// Per tile (2048 edges): LDS-group by bucket, append each group contiguously
// to the global bucket array with ONE atomicAdd per bucket per tile -> writes
// are ~256B contiguous runs instead of random 4B (fixes 16x write amp).
__global__ __launch_bounds__(256) void bucketA_kernel(
    const int* __restrict__ rows, const int* __restrict__ cols, const float* __restrict__ vals,
    int estart, int eend,
    unsigned* __restrict__ gW, unsigned short* __restrict__ gR, int* __restrict__ gFill)
{
    __shared__ int cnt[ABK], base[ABK], gpos[ABK], rank[ABK];
    __shared__ unsigned bufW[ATILE];
    __shared__ unsigned short bufR[ATILE];
    __shared__ unsigned char bufB[ATILE];

    int e0 = estart + blockIdx.x * ATILE;
    int n = eend - e0; if (n > ATILE) n = ATILE;
    int tid = threadIdx.x;
    if (tid < ABK) { cnt[tid] = 0; rank[tid] = 0; }
    __syncthreads();

    unsigned w[8]; unsigned short rl[8]; unsigned char bb[8]; bool ok[8];
#pragma unroll
    for (int j = 0; j < 8; ++j) {
        int idx = tid + j * 256;
        ok[j] = idx < n;
        if (ok[j]) {
            int e = e0 + idx;
            unsigned r = (unsigned)rows[e];
            unsigned b = r / BRNG;
            bb[j] = (unsigned char)b;
            rl[j] = (unsigned short)(r - b * BRNG);
            w[j]  = (((unsigned)(unsigned short)f2bf(vals[e])) << 17) | (unsigned)cols[e];
            atomicAdd(&cnt[b], 1);
        }
    }
    __syncthreads();
    if (tid == 0) {
        int run = 0;
        for (int k = 0; k < ABK; ++k) { base[k] = run; run += cnt[k]; }
    }
    __syncthreads();
    if (tid < ABK) gpos[tid] = atomicAdd(gFill + tid, cnt[tid]);
#pragma unroll
    for (int j = 0; j < 8; ++j) {
        if (ok[j]) {
            int b = bb[j];
            int p = base[b] + atomicAdd(&rank[b], 1);
            bufW[p] = w[j]; bufR[p] = rl[j]; bufB[p] = (unsigned char)b;
        }
    }
    __syncthreads();
    for (int i = tid; i < n; i += 256) {
        int b = bufB[i];
        int dst = gpos[b] + (i - base[b]);
        if (dst < ACAP) {                       // paranoia: never cross bucket
            gW[b * ACAP + dst] = bufW[i];
            gR[b * ACAP + dst] = bufR[i];
        }
    }
}

// ---------------- phase B: scatter within buckets -> CSR -------------------
// Bucket k's destination window in csr is ~400KB (3125 rows * ~32 entries).
// Buckets pinned to XCDs via blockIdx&7 so the window stays L2-resident and
// 64B lines accumulate all 16 entries before writeback.
__global__ __launch_bounds__(256) void bucketB_kernel(
    const unsigned* __restrict__ gW, const unsigned short* __restrict__ gR,
    const int* __restrict__ gFill, const int* __restrict__ rp,
    int* __restrict__ fill, unsigned* __restrict__ csr)
{
    int myx = blockIdx.x & 7;
    int gslot = blockIdx.x >> 3;               // 0..127
#pragma unroll
    for (int j = 0; j < 4; ++j) {
        int b = myx + 8 * j;
        int n = gFill[b]; if (n > ACAP) n = ACAP;
        int s0 = (int)((long long)n * gslot / 128);
        int s1 = (int)((long long)n * (gslot + 1) / 128);
        for (int i = s0 + threadIdx.x; i < s1; i += 256) {
            unsigned w = gW[b * ACAP + i];
            int r = b * BRNG + (int)gR[b * ACAP + i];
            int p = rp[r] + atomicAdd(fill + r, 1);
            csr[p] = w;
        }
    }
}

// ------------------------- gather SpMM (packed CSR) ------------------------
// half-wave (32 lanes = 32 dims) per output row; 4-edge unroll, 2 acc chains
__global__ __launch_bounds__(256) void spmm_csr_kernel(
    const int* __restrict__ rp, const unsigned* __restrict__ csr,
    const float* __restrict__ X, float* __restrict__ out, int accum)
{
    int r = blockIdx.x * 8 + (threadIdx.x >> 5);
    int d = threadIdx.x & 31;
    int s = rp[r], e = rp[r + 1];
    float acc = accum ? out[(size_t)r * DIM + d] : 0.f;
    float acc2 = 0.f;
    int i = s;
    for (; i + 3 < e; i += 4) {
        unsigned a = csr[i];
        unsigned b = csr[i + 1];
        unsigned c = csr[i + 2];
        unsigned dd = csr[i + 3];
        acc  += s2f((short)(a >> 17))  * X[(size_t)(a & 0x1FFFF) * DIM + d];
        acc2 += s2f((short)(b >> 17))  * X[(size_t)(b & 0x1FFFF) * DIM + d];
        acc  += s2f((short)(c >> 17))  * X[(size_t)(c & 0x1FFFF) * DIM + d];
        acc2 += s2f((short)(dd >> 17)) * X[(size_t)(dd & 0x1FFFF) * DIM + d];
    }
    for (; i < e; ++i) {
        unsigned a = csr[i];
        acc += s2f((short)(a >> 17)) * X[(size_t)(a & 0x1FFFF) * DIM + d];
    }
    out[(size_t)r * DIM + d] = acc + acc2;
}

// ---------------- fallback: atomic scatter SpMM (small ws) -----------------
__global__ __launch_bounds__(256) void atomic_spmm_kernel(
    const int* __restrict__ rows, const int* __restrict__ cols,
    const float* __restrict__ vals, const float* __restrict__ X,
    float* __restrict__ out, int ne)
{
    int e = blockIdx.x * 8 + (threadIdx.x >> 5);
    if (e >= ne) return;
    int d = threadIdx.x & 31;
    int r = rows[e], c = cols[e];
    atomicAdd(out + (size_t)r * DIM + d, vals[e] * X[(size_t)c * DIM + d]);
}

// ----------------------------- pair dots -----------------------------------
__global__ __launch_bounds__(256) void pairs_kernel(
    const float* __restrict__ ACC, const float* __restrict__ IF,
    const int* __restrict__ ui, const int* __restrict__ ii,
    float* __restrict__ out)
{
    int p = blockIdx.x * 8 + (threadIdx.x >> 5);
    int d = threadIdx.x & 31;
    int u = ui[p], it = ii[p];
    float v = ACC[(size_t)u * DIM + d] * IF[(size_t)it * DIM + d];
    v += __shfl_xor(v, 1);
    v += __shfl_xor(v, 2);
    v += __shfl_xor(v, 4);
    v += __shfl_xor(v, 8);
    v += __shfl_xor(v, 16);
    if (d == 0) {
        out[p] = v;
        out[NP + p] = 1.f / (1.f + expf(-v));
    }
}

// ---------------------------------------------------------------------------
extern "C" void kernel_launch(void* const* d_in, const int* in_sizes, int n_in,
                              void* d_out, int out_size, void* d_ws, size_t ws_size,
                              hipStream_t stream)
{
    const float* Xu   = (const float*)d_in[0];   // user_features f32
    const float* Xi   = (const float*)d_in[1];   // item_features f32
    const float* uemb = (const float*)d_in[2];
    const float* iemb = (const float*)d_in[3];
    const float* W    = (const float*)d_in[4];
    const float* bias = (const float*)d_in[5];
    const int*   sr   = (const int*)d_in[6];
    const int*   sc   = (const int*)d_in[7];
    const float* sv   = (const float*)d_in[8];
    const int*   ur   = (const int*)d_in[9];
    const int*   uc   = (const int*)d_in[10];
    const float* uv   = (const float*)d_in[11];
    const int*   uidx = (const int*)d_in[12];
    const int*   iidx = (const int*)d_in[13];
    float* out = (float*)d_out;
    (void)in_sizes; (void)n_in; (void)out_size;

    char* ws = (char*)d_ws;

    // ---- CSR-path layout: ~60.0 MB (bucket arrays overlay dead ACC) ----
    size_t o = 0;
    auto alloc = [&](size_t b) { size_t r = o; o = (o + b + 255) & ~(size_t)255; return r; };
    size_t oStats = alloc(64 * 4);
    size_t oWsum  = alloc(32 * 4);
    size_t oCntS  = alloc((size_t)NU * 4);
    size_t oCntU  = alloc((size_t)NU * 4);
    size_t oFillS = alloc((size_t)NU * 4);
    size_t oFillU = alloc((size_t)NU * 4);
    size_t oBFill = alloc(4 * ABK * 4);          // 4 phase-sets of bucket fills
    size_t oCsS   = alloc(128 * 4);
    size_t oCsU   = alloc(128 * 4);
    size_t oRpS   = alloc((size_t)(NU + 1) * 4);
    size_t oRpU   = alloc((size_t)(NU + 1) * 4);
    size_t oACC   = alloc((size_t)NU * DIM * 4); // buckets overlay this (9.98MB<=12.8MB)
    size_t oUF    = alloc((size_t)NU * DIM * 4);
    size_t oIF    = alloc((size_t)NI * DIM * 4);
    size_t oCsrS  = alloc((size_t)ES * 4);
    size_t oCsrU  = alloc((size_t)EU * 4);       // H1 overlays this (both 12.8 MB)
    size_t csr_total = o;

    if (ws_size >= csr_total) {
        float*    stats = (float*)(ws + oStats);
        float*    wsum  = (float*)(ws + oWsum);
        int*      cntS  = (int*)(ws + oCntS);
        int*      cntU  = (int*)(ws + oCntU);
        int*      fillS = (int*)(ws + oFillS);
        int*      fillU = (int*)(ws + oFillU);
        int*      bf    = (int*)(ws + oBFill);
        int*      csS   = (int*)(ws + oCsS);
        int*      csU   = (int*)(ws + oCsU);
        int*      rpS   = (int*)(ws + oRpS);
        int*      rpU   = (int*)(ws + oRpU);
        float*    ACC   = (float*)(ws + oACC);
        float*    UF    = (float*)(ws + oUF);
        float*    IF    = (float*)(ws + oIF);
        unsigned* csrS  = (unsigned*)(ws + oCsrS);
        unsigned* csrU  = (unsigned*)(ws + oCsrU);
        float*    H1    = (float*)(ws + oCsrU);   // overlay: valid after item SpMM
        // bucket arrays overlay ACC: u32 part then u16 part (offset 6656000, 256-aligned)
        unsigned*       gW = (unsigned*)(ws + oACC);
        unsigned short* gR = (unsigned short*)(ws + oACC + (size_t)ABK * ACAP * 4);

        hipMemsetAsync(ws, 0, oCsS, stream);   // stats/wsum/cnt/fill/bucketFill

        wsum_kernel<<<1, 64, 0, stream>>>(W, wsum);
        gemm_stats_kernel<<<1563, 256, 0, stream>>>(Xu, W, UF, stats + 0, stats + 1, NU);
        gemm_stats_kernel<<<782, 256, 0, stream>>>(Xi, W, IF, stats + 2, stats + 3, NI);
        signorm_kernel<<<1024, 256, 0, stream>>>(UF, NU * DIM / 4, (float)((size_t)NU * NF),
                                                 stats + 0, wsum, bias, stats + 4);
        signorm_kernel<<<512, 256, 0, stream>>>(IF, NI * DIM / 4, (float)((size_t)NI * NF),
                                                stats + 2, wsum, bias, stats + 6);
        fusion_kernel<<<1024, 256, 0, stream>>>(UF, uemb, NU * DIM / 4, (float)(NU * DIM), stats + 4);
        fusion_kernel<<<512, 256, 0, stream>>>(IF, iemb, NI * DIM / 4, (float)(NI * DIM), stats + 6);

        hist_kernel<<<(ES + EU) / 256, 256, 0, stream>>>(sr, ur, cntS, cntU);
        chunksum_kernel<<<2 * NCH, 256, 0, stream>>>(cntS, cntU, csS, csU);
        scan_offsets_kernel<<<1, 64, 0, stream>>>(csS, csU, rpS, rpU);
        chunkscan_kernel<<<2 * NCH, 1024, 0, stream>>>(cntS, cntU, csS, csU, rpS, rpU);

        const int AGRID = (EHALF + ATILE - 1) / ATILE;   // 782
        // U matrix first (item SpMM reads csrU before H1 overlays it)
        bucketA_kernel<<<AGRID, 256, 0, stream>>>(ur, uc, uv, 0, EHALF, gW, gR, bf + 0);
        bucketB_kernel<<<1024, 256, 0, stream>>>(gW, gR, bf + 0, rpU, fillU, csrU);
        bucketA_kernel<<<AGRID, 256, 0, stream>>>(ur, uc, uv, EHALF, EU, gW, gR, bf + ABK);
        bucketB_kernel<<<1024, 256, 0, stream>>>(gW, gR, bf + ABK, rpU, fillU, csrU);
        bucketA_kernel<<<AGRID, 256, 0, stream>>>(sr, sc, sv, 0, EHALF, gW, gR, bf + 2 * ABK);
        bucketB_kernel<<<1024, 256, 0, stream>>>(gW, gR, bf + 2 * ABK, rpS, fillS, csrS);
        bucketA_kernel<<<AGRID, 256, 0, stream>>>(sr, sc, sv, EHALF, ES, gW, gR, bf + 3 * ABK);
        bucketB_kernel<<<1024, 256, 0, stream>>>(gW, gR, bf + 3 * ABK, rpS, fillS, csrS);

        // order matters: item SpMM writes ACC (bucket arrays dead now)
        spmm_csr_kernel<<<NU / 8, 256, 0, stream>>>(rpU, csrU, IF, ACC, 0); // item_consumed
        spmm_csr_kernel<<<NU / 8, 256, 0, stream>>>(rpS, csrS, UF, H1, 0);  // h1 (overlays csrU)
        spmm_csr_kernel<<<NU / 8, 256, 0, stream>>>(rpS, csrS, H1, ACC, 1); // h2 += into ACC

        pairs_kernel<<<NP / 8, 256, 0, stream>>>(ACC, IF, uidx, iidx, out);
    } else {
        // ---- atomic fallback layout: ~44.8 MB ----
        size_t o2 = 0;
        auto alloc2 = [&](size_t b) { size_t r = o2; o2 = (o2 + b + 255) & ~(size_t)255; return r; };
        size_t aStats = alloc2(64 * 4);
        size_t aWsum  = alloc2(32 * 4);
        size_t aACC   = alloc2((size_t)NU * DIM * 4);
        size_t aH1    = alloc2((size_t)NU * DIM * 4);
        size_t aUF    = alloc2((size_t)NU * DIM * 4);
        size_t aIF    = alloc2((size_t)NI * DIM * 4);

        float* stats = (float*)(ws + aStats);
        float* wsum  = (float*)(ws + aWsum);
        float* ACC   = (float*)(ws + aACC);
        float* H1    = (float*)(ws + aH1);
        float* UF    = (float*)(ws + aUF);
        float* IF    = (float*)(ws + aIF);

        hipMemsetAsync(ws, 0, 512, stream);                              // stats (+wsum)
        hipMemsetAsync(ws + aACC, 0, (size_t)NU * DIM * 8, stream);      // ACC + H1

        wsum_kernel<<<1, 64, 0, stream>>>(W, wsum);
        gemm_stats_kernel<<<1563, 256, 0, stream>>>(Xu, W, UF, stats + 0, stats + 1, NU);
        gemm_stats_kernel<<<782, 256, 0, stream>>>(Xi, W, IF, stats + 2, stats + 3, NI);
        signorm_kernel<<<1024, 256, 0, stream>>>(UF, NU * DIM / 4, (float)((size_t)NU * NF),
                                                 stats + 0, wsum, bias, stats + 4);
        signorm_kernel<<<512, 256, 0, stream>>>(IF, NI * DIM / 4, (float)((size_t)NI * NF),
                                                stats + 2, wsum, bias, stats + 6);
        fusion_kernel<<<1024, 256, 0, stream>>>(UF, uemb, NU * DIM / 4, (float)(NU * DIM), stats + 4);
        fusion_kernel<<<512, 256, 0, stream>>>(IF, iemb, NI * DIM / 4, (float)(NI * DIM), stats + 6);

        atomic_spmm_kernel<<<EU / 8, 256, 0, stream>>>(ur, uc, uv, IF, ACC, EU); // item_consumed
        atomic_spmm_kernel<<<ES / 8, 256, 0, stream>>>(sr, sc, sv, UF, H1, ES);  // h1
        atomic_spmm_kernel<<<ES / 8, 256, 0, stream>>>(sr, sc, sv, H1, ACC, ES); // h2

        pairs_kernel<<<NP / 8, 256, 0, stream>>>(ACC, IF, uidx, iidx, out);
    }
}

// Round 2
// 1540.986 us; speedup vs baseline: 1.1421x; 1.1046x over previous
//
#include <hip/hip_runtime.h>
#include <hip/hip_bf16.h>

#define NU 100000
#define NI 50000
#define NF 512
#define DIM 32
#define ES 3200000
#define EU 3200000
#define NP 1000000
#define CHUNK 1024
#define NCH 98   // ceil(NU/CHUNK)

// ---- bucketed scatter params ----
#define ABK 32          // buckets per matrix
#define BRNG 3125       // rows per bucket; 32*3125 == 100000 exactly
#define EHALF 1600000   // edges per half-phase (exactly EU/2 == ES/2)
#define ACAP 52000      // per-bucket capacity per half (mean 50000, +9 sigma)
#define ATILE 2048      // edges per phase-A block
#define HSUB 8          // hist sub-blocks per bucket

typedef short bf16x8 __attribute__((ext_vector_type(8)));
typedef float f32x4 __attribute__((ext_vector_type(4)));

__device__ __forceinline__ float s2f(short s) {
    unsigned u = ((unsigned)(unsigned short)s) << 16;
    return __uint_as_float(u);
}
// f32 -> bf16 bits, round-to-nearest-even (inputs are finite; no NaN path)
__device__ __forceinline__ short f2bf(float f) {
    unsigned u = __float_as_uint(f);
    return (short)((u + 0x7FFFu + ((u >> 16) & 1u)) >> 16);
}

// ---------------- colsum of W (512x32 f32) -> wsum[32] f32 ----------------
__global__ void wsum_kernel(const float* __restrict__ W, float* __restrict__ wsum) {
    int c = threadIdx.x;
    if (c >= DIM) return;
    float s = 0.f;
    for (int k = 0; k < NF; ++k) s += W[k * DIM + c];
    wsum[c] = s;
}

// ------------- MFMA GEMM: RAW = bf16(X) @ bf16(W)  (+ sum/sumsq of X) ------
__global__ __launch_bounds__(256) void gemm_stats_kernel(
    const float* __restrict__ X, const float* __restrict__ W,
    float* __restrict__ RAW, float* __restrict__ statSum, float* __restrict__ statSq,
    int M)
{
    __shared__ short bfrag[16384];  // 16 ksteps x 2 ntiles x 64 lanes x 8 bf16
    for (int idx = threadIdx.x; idx < 16384; idx += 256) {
        int j = idx & 7;
        int lane = (idx >> 3) & 63;
        int t = (idx >> 9) & 1;
        int s = idx >> 10;
        int k = s * 32 + ((lane >> 4) << 3) + j;   // B[k][n]: k = quad*8+j per kstep
        int n = t * 16 + (lane & 15);
        bfrag[idx] = f2bf(W[k * DIM + n]);
    }
    __syncthreads();

    const int wave = threadIdx.x >> 6;
    const int lane = threadIdx.x & 63;
    const int quad = lane >> 4;
    const int mrow = lane & 15;

    bf16x8 ones;
#pragma unroll
    for (int j = 0; j < 8; ++j) ones[j] = (short)0x3F80;  // bf16 1.0

    float lsum = 0.f, lsq = 0.f;
    const int nstrips = M >> 4;
    for (int strip = blockIdx.x * 4 + wave; strip < nstrips; strip += gridDim.x * 4) {
        const float* arow = X + (size_t)(strip * 16 + mrow) * NF + quad * 8;
        f32x4 acc0 = {0.f, 0.f, 0.f, 0.f};
        f32x4 acc1 = {0.f, 0.f, 0.f, 0.f};
        f32x4 accR = {0.f, 0.f, 0.f, 0.f};
        f32x4 accG = {0.f, 0.f, 0.f, 0.f};
#pragma unroll
        for (int s = 0; s < 16; ++s) {
            float4 a0 = *(const float4*)(arow + s * 32);
            float4 a1 = *(const float4*)(arow + s * 32 + 4);
            bf16x8 a;
            a[0] = f2bf(a0.x); a[1] = f2bf(a0.y); a[2] = f2bf(a0.z); a[3] = f2bf(a0.w);
            a[4] = f2bf(a1.x); a[5] = f2bf(a1.y); a[6] = f2bf(a1.z); a[7] = f2bf(a1.w);
            bf16x8 b0 = *(const bf16x8*)(bfrag + (s * 2 + 0) * 512 + lane * 8);
            bf16x8 b1 = *(const bf16x8*)(bfrag + (s * 2 + 1) * 512 + lane * 8);
            acc0 = __builtin_amdgcn_mfma_f32_16x16x32_bf16(a, b0, acc0, 0, 0, 0);
            acc1 = __builtin_amdgcn_mfma_f32_16x16x32_bf16(a, b1, acc1, 0, 0, 0);
            accR = __builtin_amdgcn_mfma_f32_16x16x32_bf16(a, ones, accR, 0, 0, 0);
            accG = __builtin_amdgcn_mfma_f32_16x16x32_bf16(a, a, accG, 0, 0, 0);
        }
        float* outp = RAW + (size_t)strip * 16 * DIM;
#pragma unroll
        for (int i = 0; i < 4; ++i) {
            int r = quad * 4 + i;        // C/D: row = quad*4 + reg, col = lane&15
            outp[r * DIM + mrow]      = acc0[i];
            outp[r * DIM + 16 + mrow] = acc1[i];
        }
        if (mrow == 0) lsum += (accR[0] + accR[1]) + (accR[2] + accR[3]);
        int dg = mrow - quad * 4;        // Gram diagonal: col==row -> row sumsq
        if (dg >= 0 && dg < 4) lsq += accG[dg];
    }
#pragma unroll
    for (int off = 32; off > 0; off >>= 1) {
        lsum += __shfl_down(lsum, off);
        lsq  += __shfl_down(lsq, off);
    }
    if (lane == 0) { atomicAdd(statSum, lsum); atomicAdd(statSq, lsq); }
}

// ---- z=(raw - mu*wsum_c)/sigma + b_c; s=sigmoid(z); buf=s; stats of s -----
__global__ __launch_bounds__(256) void signorm_kernel(
    float* __restrict__ buf, int n4, float nx,
    const float* __restrict__ statsIn, const float* __restrict__ wsum,
    const float* __restrict__ bias, float* __restrict__ statsOut)
{
    float mu  = statsIn[0] / nx;
    float var = (statsIn[1] - nx * mu * mu) / (nx - 1.f);
    float inv = 1.f / sqrtf(var);
    float ls = 0.f, lsq = 0.f;
    int stride = gridDim.x * blockDim.x;
    for (int i = blockIdx.x * blockDim.x + threadIdx.x; i < n4; i += stride) {
        float4 v = ((const float4*)buf)[i];
        int c0 = (i << 2) & 31;
        float4 r;
        r.x = 1.f / (1.f + expf(-((v.x - mu * wsum[c0 + 0]) * inv + bias[c0 + 0])));
        r.y = 1.f / (1.f + expf(-((v.y - mu * wsum[c0 + 1]) * inv + bias[c0 + 1])));
        r.z = 1.f / (1.f + expf(-((v.z - mu * wsum[c0 + 2]) * inv + bias[c0 + 2])));
        r.w = 1.f / (1.f + expf(-((v.w - mu * wsum[c0 + 3]) * inv + bias[c0 + 3])));
        ((float4*)buf)[i] = r;
        ls  += (r.x + r.y) + (r.z + r.w);
        lsq += (r.x * r.x + r.y * r.y) + (r.z * r.z + r.w * r.w);
    }
#pragma unroll
    for (int off = 32; off > 0; off >>= 1) {
        ls  += __shfl_down(ls, off);
        lsq += __shfl_down(lsq, off);
    }
    if ((threadIdx.x & 63) == 0) { atomicAdd(statsOut + 0, ls); atomicAdd(statsOut + 1, lsq); }
}

// ----------- buf = (buf - mu)/sigma + emb  (global normalize of s) ---------
__global__ __launch_bounds__(256) void fusion_kernel(
    float* __restrict__ buf, const float* __restrict__ emb, int n4, float n,
    const float* __restrict__ statsIn)
{
    float mu  = statsIn[0] / n;
    float var = (statsIn[1] - n * mu * mu) / (n - 1.f);
    float inv = 1.f / sqrtf(var);
    int stride = gridDim.x * blockDim.x;
    for (int i = blockIdx.x * blockDim.x + threadIdx.x; i < n4; i += stride) {
        float4 v = ((const float4*)buf)[i];
        float4 e = ((const float4*)emb)[i];
        v.x = (v.x - mu) * inv + e.x;
        v.y = (v.y - mu) * inv + e.y;
        v.z = (v.z - mu) * inv + e.z;
        v.w = (v.w - mu) * inv + e.w;
        ((float4*)buf)[i] = v;
    }
}

// ---------------- phase A: partition edges into 32 row-buckets -------------
// Record: u32 w = (bf16(val)<<17)|col  (identical to final CSR word),
//         u16 rl = row - bucket*BRNG.
__global__ __launch_bounds__(256) void bucketA_kernel(
    const int* __restrict__ rows, const int* __restrict__ cols, const float* __restrict__ vals,
    int estart, int eend,
    unsigned* __restrict__ gW, unsigned short* __restrict__ gR, int* __restrict__ gFill)
{
    __shared__ int cnt[ABK], base[ABK], gpos[ABK], rank[ABK];
    __shared__ unsigned bufW[ATILE];
    __shared__ unsigned short bufR[ATILE];
    __shared__ unsigned char bufB[ATILE];

    int e0 = estart + blockIdx.x * ATILE;
    int n = eend - e0; if (n > ATILE) n = ATILE;
    int tid = threadIdx.x;
    if (tid < ABK) { cnt[tid] = 0; rank[tid] = 0; }
    __syncthreads();

    unsigned w[8]; unsigned short rl[8]; unsigned char bb[8]; bool ok[8];
#pragma unroll
    for (int j = 0; j < 8; ++j) {
        int idx = tid + j * 256;
        ok[j] = idx < n;
        if (ok[j]) {
            int e = e0 + idx;
            unsigned r = (unsigned)rows[e];
            unsigned b = r / BRNG;
            bb[j] = (unsigned char)b;
            rl[j] = (unsigned short)(r - b * BRNG);
            w[j]  = (((unsigned)(unsigned short)f2bf(vals[e])) << 17) | (unsigned)cols[e];
            atomicAdd(&cnt[b], 1);
        }
    }
    __syncthreads();
    if (tid == 0) {
        int run = 0;
        for (int k = 0; k < ABK; ++k) { base[k] = run; run += cnt[k]; }
    }
    __syncthreads();
    if (tid < ABK) gpos[tid] = atomicAdd(gFill + tid, cnt[tid]);
#pragma unroll
    for (int j = 0; j < 8; ++j) {
        if (ok[j]) {
            int b = bb[j];
            int p = base[b] + atomicAdd(&rank[b], 1);
            bufW[p] = w[j]; bufR[p] = rl[j]; bufB[p] = (unsigned char)b;
        }
    }
    __syncthreads();
    for (int i = tid; i < n; i += 256) {
        int b = bufB[i];
        int dst = gpos[b] + (i - base[b]);
        if (dst < ACAP) {                       // paranoia: never cross bucket
            gW[b * ACAP + dst] = bufW[i];
            gR[b * ACAP + dst] = bufR[i];
        }
    }
}

// -------- per-row counts from bucketed gR (replaces raw-row hist) ----------
// HSUB sub-blocks per bucket; all sub-blocks of a bucket share one XCD
// (blockIdx&7 == bucket&7). LDS histogram of 3125 counters, then coalesced
// atomics confined to the bucket's 12.5KB cnt window (L2-resident).
__global__ __launch_bounds__(256) void bucket_hist_kernel(
    const unsigned short* __restrict__ gR, const int* __restrict__ gFill,
    int* __restrict__ cnt)
{
    __shared__ int h[BRNG];
    int x = blockIdx.x;
    int b = (x & 7) + 8 * ((x >> 6) & 3);      // bucket; b&7 == x&7 (XCD pin)
    int sub = (x >> 3) & 7;
    for (int i = threadIdx.x; i < BRNG; i += 256) h[i] = 0;
    __syncthreads();
    int n = gFill[b]; if (n > ACAP) n = ACAP;
    int s0 = (int)((long long)n * sub / HSUB);
    int s1 = (int)((long long)n * (sub + 1) / HSUB);
    for (int i = s0 + threadIdx.x; i < s1; i += 256)
        atomicAdd(&h[gR[b * ACAP + i]], 1);
    __syncthreads();
    int base = b * BRNG;
    for (int i = threadIdx.x; i < BRNG; i += 256) {
        int v = h[i];
        if (v) atomicAdd(cnt + base + i, v);
    }
}

// --------------------------- scan chain (per half) -------------------------
__global__ void chunksum_kernel(const int* __restrict__ cnt, int* __restrict__ cs)
{
    int c = blockIdx.x;
    int base = c * CHUNK;
    int v = 0;
    for (int t = threadIdx.x; t < CHUNK; t += 256) {
        int i = base + t;
        if (i < NU) v += cnt[i];
    }
#pragma unroll
    for (int off = 32; off > 0; off >>= 1) v += __shfl_down(v, off);
    __shared__ int sm[4];
    if ((threadIdx.x & 63) == 0) sm[threadIdx.x >> 6] = v;
    __syncthreads();
    if (threadIdx.x == 0) cs[c] = sm[0] + sm[1] + sm[2] + sm[3];
}

__global__ void scan_offsets_kernel(int* __restrict__ cs, int* __restrict__ rp)
{
    if (threadIdx.x == 0) {
        int run = 0;
        for (int c = 0; c < NCH; ++c) { int t = cs[c]; cs[c] = run; run += t; }
        rp[NU] = run;
    }
}

// computes rp (exclusive scan), then zeroes cnt and fill for the next half
__global__ __launch_bounds__(1024) void chunkscan_kernel(
    int* __restrict__ cnt, const int* __restrict__ cs,
    int* __restrict__ rp, int* __restrict__ fill)
{
    int c = blockIdx.x;
    int i = c * CHUNK + threadIdx.x;
    int v = (i < NU) ? cnt[i] : 0;
    __shared__ int sm[CHUNK];
    sm[threadIdx.x] = v;
    __syncthreads();
    for (int off = 1; off < CHUNK; off <<= 1) {
        int t = (threadIdx.x >= off) ? sm[threadIdx.x - off] : 0;
        __syncthreads();
        sm[threadIdx.x] += t;
        __syncthreads();
    }
    if (i < NU) {
        rp[i] = cs[c] + sm[threadIdx.x] - v;  // exclusive scan
        cnt[i] = 0;                            // recycle for next half
        fill[i] = 0;
    }
}

// ---------------- phase B: scatter within buckets -> CSR half-segment ------
__global__ __launch_bounds__(256) void bucketB_kernel(
    const unsigned* __restrict__ gW, const unsigned short* __restrict__ gR,
    const int* __restrict__ gFill, const int* __restrict__ rp,
    int* __restrict__ fill, unsigned* __restrict__ csr)
{
    int myx = blockIdx.x & 7;
    int gslot = blockIdx.x >> 3;               // 0..127
#pragma unroll
    for (int j = 0; j < 4; ++j) {
        int b = myx + 8 * j;
        int n = gFill[b]; if (n > ACAP) n = ACAP;
        int s0 = (int)((long long)n * gslot / 128);
        int s1 = (int)((long long)n * (gslot + 1) / 128);
        for (int i = s0 + threadIdx.x; i < s1; i += 256) {
            unsigned w = gW[b * ACAP + i];
            int r = b * BRNG + (int)gR[b * ACAP + i];
            int p = rp[r] + atomicAdd(fill + r, 1);
            csr[p] = w;
        }
    }
}

// ------------------------- gather SpMM (packed CSR, 2 segments) ------------
__device__ __forceinline__ void spmm_seg(
    const unsigned* __restrict__ csr, int s, int e,
    const float* __restrict__ X, int d, float& acc, float& acc2)
{
    int i = s;
    for (; i + 3 < e; i += 4) {
        unsigned a = csr[i];
        unsigned b = csr[i + 1];
        unsigned c = csr[i + 2];
        unsigned dd = csr[i + 3];
        acc  += s2f((short)(a >> 17))  * X[(size_t)(a & 0x1FFFF) * DIM + d];
        acc2 += s2f((short)(b >> 17))  * X[(size_t)(b & 0x1FFFF) * DIM + d];
        acc  += s2f((short)(c >> 17))  * X[(size_t)(c & 0x1FFFF) * DIM + d];
        acc2 += s2f((short)(dd >> 17)) * X[(size_t)(dd & 0x1FFFF) * DIM + d];
    }
    for (; i < e; ++i) {
        unsigned a = csr[i];
        acc += s2f((short)(a >> 17)) * X[(size_t)(a & 0x1FFFF) * DIM + d];
    }
}

__global__ __launch_bounds__(256) void spmm_csr_kernel(
    const int* __restrict__ rp0, const int* __restrict__ rp1,
    const unsigned* __restrict__ csr,
    const float* __restrict__ X, float* __restrict__ out, int accum)
{
    int r = blockIdx.x * 8 + (threadIdx.x >> 5);
    int d = threadIdx.x & 31;
    float acc = accum ? out[(size_t)r * DIM + d] : 0.f;
    float acc2 = 0.f;
    spmm_seg(csr, rp0[r], rp0[r + 1], X, d, acc, acc2);
    spmm_seg(csr, EHALF + rp1[r], EHALF + rp1[r + 1], X, d, acc, acc2);
    out[(size_t)r * DIM + d] = acc + acc2;
}

// ---------------- fallback: atomic scatter SpMM (small ws) -----------------
__global__ __launch_bounds__(256) void atomic_spmm_kernel(
    const int* __restrict__ rows, const int* __restrict__ cols,
    const float* __restrict__ vals, const float* __restrict__ X,
    float* __restrict__ out, int ne)
{
    int e = blockIdx.x * 8 + (threadIdx.x >> 5);
    if (e >= ne) return;
    int d = threadIdx.x & 31;
    int r = rows[e], c = cols[e];
    atomicAdd(out + (size_t)r * DIM + d, vals[e] * X[(size_t)c * DIM + d]);
}

// ----------------------------- pair dots -----------------------------------
__global__ __launch_bounds__(256) void pairs_kernel(
    const float* __restrict__ ACC, const float* __restrict__ IF,
    const int* __restrict__ ui, const int* __restrict__ ii,
    float* __restrict__ out)
{
    int p = blockIdx.x * 8 + (threadIdx.x >> 5);
    int d = threadIdx.x & 31;
    int u = ui[p], it = ii[p];
    float v = ACC[(size_t)u * DIM + d] * IF[(size_t)it * DIM + d];
    v += __shfl_xor(v, 1);
    v += __shfl_xor(v, 2);
    v += __shfl_xor(v, 4);
    v += __shfl_xor(v, 8);
    v += __shfl_xor(v, 16);
    if (d == 0) {
        out[p] = v;
        out[NP + p] = 1.f / (1.f + expf(-v));
    }
}

// ---------------------------------------------------------------------------
extern "C" void kernel_launch(void* const* d_in, const int* in_sizes, int n_in,
                              void* d_out, int out_size, void* d_ws, size_t ws_size,
                              hipStream_t stream)
{
    const float* Xu   = (const float*)d_in[0];   // user_features f32
    const float* Xi   = (const float*)d_in[1];   // item_features f32
    const float* uemb = (const float*)d_in[2];
    const float* iemb = (const float*)d_in[3];
    const float* W    = (const float*)d_in[4];
    const float* bias = (const float*)d_in[5];
    const int*   sr   = (const int*)d_in[6];
    const int*   sc   = (const int*)d_in[7];
    const float* sv   = (const float*)d_in[8];
    const int*   ur   = (const int*)d_in[9];
    const int*   uc   = (const int*)d_in[10];
    const float* uv   = (const float*)d_in[11];
    const int*   uidx = (const int*)d_in[12];
    const int*   iidx = (const int*)d_in[13];
    float* out = (float*)d_out;
    (void)in_sizes; (void)n_in; (void)out_size;

    char* ws = (char*)d_ws;

    // ---- CSR-path layout: ~60.0 MB (bucket arrays overlay dead ACC) ----
    size_t o = 0;
    auto alloc = [&](size_t b) { size_t r = o; o = (o + b + 255) & ~(size_t)255; return r; };
    size_t oStats = alloc(64 * 4);
    size_t oWsum  = alloc(32 * 4);
    size_t oCnt   = alloc((size_t)NU * 4);       // recycled across 4 halves
    size_t oFill  = alloc((size_t)NU * 4);       // recycled across 4 halves
    size_t oBFill = alloc(4 * ABK * 4);          // 4 half-sets of bucket fills
    size_t oCs    = alloc(128 * 4);
    size_t oRpU0  = alloc((size_t)(NU + 1) * 4);
    size_t oRpU1  = alloc((size_t)(NU + 1) * 4);
    size_t oRpS0  = alloc((size_t)(NU + 1) * 4);
    size_t oRpS1  = alloc((size_t)(NU + 1) * 4);
    size_t oACC   = alloc((size_t)NU * DIM * 4); // buckets overlay this (9.98MB<=12.8MB)
    size_t oUF    = alloc((size_t)NU * DIM * 4);
    size_t oIF    = alloc((size_t)NI * DIM * 4);
    size_t oCsrS  = alloc((size_t)ES * 4);
    size_t oCsrU  = alloc((size_t)EU * 4);       // H1 overlays this (both 12.8 MB)
    size_t csr_total = o;

    if (ws_size >= csr_total) {
        float*    stats = (float*)(ws + oStats);
        float*    wsum  = (float*)(ws + oWsum);
        int*      cnt   = (int*)(ws + oCnt);
        int*      fill  = (int*)(ws + oFill);
        int*      bf    = (int*)(ws + oBFill);
        int*      cs    = (int*)(ws + oCs);
        int*      rpU0  = (int*)(ws + oRpU0);
        int*      rpU1  = (int*)(ws + oRpU1);
        int*      rpS0  = (int*)(ws + oRpS0);
        int*      rpS1  = (int*)(ws + oRpS1);
        float*    ACC   = (float*)(ws + oACC);
        float*    UF    = (float*)(ws + oUF);
        float*    IF    = (float*)(ws + oIF);
        unsigned* csrS  = (unsigned*)(ws + oCsrS);
        unsigned* csrU  = (unsigned*)(ws + oCsrU);
        float*    H1    = (float*)(ws + oCsrU);   // overlay: valid after item SpMM
        // bucket arrays overlay ACC: u32 part then u16 part (256-aligned)
        unsigned*       gW = (unsigned*)(ws + oACC);
        unsigned short* gR = (unsigned short*)(ws + oACC + (size_t)ABK * ACAP * 4);

        hipMemsetAsync(ws, 0, oCs, stream);   // stats/wsum/cnt/fill/bucketFill

        wsum_kernel<<<1, 64, 0, stream>>>(W, wsum);
        gemm_stats_kernel<<<1563, 256, 0, stream>>>(Xu, W, UF, stats + 0, stats + 1, NU);
        gemm_stats_kernel<<<782, 256, 0, stream>>>(Xi, W, IF, stats + 2, stats + 3, NI);
        signorm_kernel<<<1024, 256, 0, stream>>>(UF, NU * DIM / 4, (float)((size_t)NU * NF),
                                                 stats + 0, wsum, bias, stats + 4);
        signorm_kernel<<<512, 256, 0, stream>>>(IF, NI * DIM / 4, (float)((size_t)NI * NF),
                                                stats + 2, wsum, bias, stats + 6);
        fusion_kernel<<<1024, 256, 0, stream>>>(UF, uemb, NU * DIM / 4, (float)(NU * DIM), stats + 4);
        fusion_kernel<<<512, 256, 0, stream>>>(IF, iemb, NI * DIM / 4, (float)(NI * DIM), stats + 6);

        const int AGRID = (EHALF + ATILE - 1) / ATILE;   // 782
        const int HGRID = ABK * HSUB;                    // 256

        // ---- U half 0 -> csrU[0, EHALF) ----
        bucketA_kernel<<<AGRID, 256, 0, stream>>>(ur, uc, uv, 0, EHALF, gW, gR, bf + 0);
        bucket_hist_kernel<<<HGRID, 256, 0, stream>>>(gR, bf + 0, cnt);
        chunksum_kernel<<<NCH, 256, 0, stream>>>(cnt, cs);
        scan_offsets_kernel<<<1, 64, 0, stream>>>(cs, rpU0);
        chunkscan_kernel<<<NCH, 1024, 0, stream>>>(cnt, cs, rpU0, fill);
        bucketB_kernel<<<1024, 256, 0, stream>>>(gW, gR, bf + 0, rpU0, fill, csrU);
        // ---- U half 1 -> csrU[EHALF, EU) ----
        bucketA_kernel<<<AGRID, 256, 0, stream>>>(ur, uc, uv, EHALF, EU, gW, gR, bf + ABK);
        bucket_hist_kernel<<<HGRID, 256, 0, stream>>>(gR, bf + ABK, cnt);
        chunksum_kernel<<<NCH, 256, 0, stream>>>(cnt, cs);
        scan_offsets_kernel<<<1, 64, 0, stream>>>(cs, rpU1);
        chunkscan_kernel<<<NCH, 1024, 0, stream>>>(cnt, cs, rpU1, fill);
        bucketB_kernel<<<1024, 256, 0, stream>>>(gW, gR, bf + ABK, rpU1, fill, csrU + EHALF);
        // ---- S half 0 -> csrS[0, EHALF) ----
        bucketA_kernel<<<AGRID, 256, 0, stream>>>(sr, sc, sv, 0, EHALF, gW, gR, bf + 2 * ABK);
        bucket_hist_kernel<<<HGRID, 256, 0, stream>>>(gR, bf + 2 * ABK, cnt);
        chunksum_kernel<<<NCH, 256, 0, stream>>>(cnt, cs);
        scan_offsets_kernel<<<1, 64, 0, stream>>>(cs, rpS0);
        chunkscan_kernel<<<NCH, 1024, 0, stream>>>(cnt, cs, rpS0, fill);
        bucketB_kernel<<<1024, 256, 0, stream>>>(gW, gR, bf + 2 * ABK, rpS0, fill, csrS);
        // ---- S half 1 -> csrS[EHALF, ES) ----
        bucketA_kernel<<<AGRID, 256, 0, stream>>>(sr, sc, sv, EHALF, ES, gW, gR, bf + 3 * ABK);
        bucket_hist_kernel<<<HGRID, 256, 0, stream>>>(gR, bf + 3 * ABK, cnt);
        chunksum_kernel<<<NCH, 256, 0, stream>>>(cnt, cs);
        scan_offsets_kernel<<<1, 64, 0, stream>>>(cs, rpS1);
        chunkscan_kernel<<<NCH, 1024, 0, stream>>>(cnt, cs, rpS1, fill);
        bucketB_kernel<<<1024, 256, 0, stream>>>(gW, gR, bf + 3 * ABK, rpS1, fill, csrS + EHALF);

        // order matters: item SpMM writes ACC (bucket arrays dead now);
        // h1 SpMM overlays csrU with H1 (csrU consumed by item SpMM first)
        spmm_csr_kernel<<<NU / 8, 256, 0, stream>>>(rpU0, rpU1, csrU, IF, ACC, 0); // item_consumed
        spmm_csr_kernel<<<NU / 8, 256, 0, stream>>>(rpS0, rpS1, csrS, UF, H1, 0);  // h1
        spmm_csr_kernel<<<NU / 8, 256, 0, stream>>>(rpS0, rpS1, csrS, H1, ACC, 1); // h2 += into ACC

        pairs_kernel<<<NP / 8, 256, 0, stream>>>(ACC, IF, uidx, iidx, out);
    } else {
        // ---- atomic fallback layout: ~44.8 MB ----
        size_t o2 = 0;
        auto alloc2 = [&](size_t b) { size_t r = o2; o2 = (o2 + b + 255) & ~(size_t)255; return r; };
        size_t aStats = alloc2(64 * 4);
        size_t aWsum  = alloc2(32 * 4);
        size_t aACC   = alloc2((size_t)NU * DIM * 4);
        size_t aH1    = alloc2((size_t)NU * DIM * 4);
        size_t aUF    = alloc2((size_t)NU * DIM * 4);
        size_t aIF    = alloc2((size_t)NI * DIM * 4);

        float* stats = (float*)(ws + aStats);
        float* wsum  = (float*)(ws + aWsum);
        float* ACC   = (float*)(ws + aACC);
        float* H1    = (float*)(ws + aH1);
        float* UF    = (float*)(ws + aUF);
        float* IF    = (float*)(ws + aIF);

        hipMemsetAsync(ws, 0, 512, stream);                              // stats (+wsum)
        hipMemsetAsync(ws + aACC, 0, (size_t)NU * DIM * 8, stream);      // ACC + H1

        wsum_kernel<<<1, 64, 0, stream>>>(W, wsum);
        gemm_stats_kernel<<<1563, 256, 0, stream>>>(Xu, W, UF, stats + 0, stats + 1, NU);
        gemm_stats_kernel<<<782, 256, 0, stream>>>(Xi, W, IF, stats + 2, stats + 3, NI);
        signorm_kernel<<<1024, 256, 0, stream>>>(UF, NU * DIM / 4, (float)((size_t)NU * NF),
                                                 stats + 0, wsum, bias, stats + 4);
        signorm_kernel<<<512, 256, 0, stream>>>(IF, NI * DIM / 4, (float)((size_t)NI * NF),
                                                stats + 2, wsum, bias, stats + 6);
        fusion_kernel<<<1024, 256, 0, stream>>>(UF, uemb, NU * DIM / 4, (float)(NU * DIM), stats + 4);
        fusion_kernel<<<512, 256, 0, stream>>>(IF, iemb, NI * DIM / 4, (float)(NI * DIM), stats + 6);

        atomic_spmm_kernel<<<EU / 8, 256, 0, stream>>>(ur, uc, uv, IF, ACC, EU); // item_consumed
        atomic_spmm_kernel<<<ES / 8, 256, 0, stream>>>(sr, sc, sv, UF, H1, ES);  // h1
        atomic_spmm_kernel<<<ES / 8, 256, 0, stream>>>(sr, sc, sv, H1, ACC, ES); // h2

        pairs_kernel<<<NP / 8, 256, 0, stream>>>(ACC, IF, uidx, iidx, out);
    }
}